// Round 11
// baseline (443.032 us; speedup 1.0000x reference)
//
#include <hip/hip_runtime.h>

#define NN 64
#define PP 8732
#define CC 91
#define MM 20
#define RATIO 3
#define BPI 8                    // match blocks per image
#define CHUNK 1092               // ceil(PP / BPI)
#define ROWS 128                 // ce rows per block
#define BTHR 512                 // ce threads per block
#define TILES2 ((NN * PP) / ROWS)   // 4366 ce tiles
#define MREP 32                  // diagnostic replication of match
#define HREP 32                  // diagnostic replication of hardneg

typedef unsigned long long u64;
typedef unsigned short u16;

// ---------------------------------------------------------------------------
// Kernel A: matching (r8 body). DIAGNOSTIC: grid x MREP; replicas write
// byte-identical values (benign). Only global block 0 zeroes the counter.
// ---------------------------------------------------------------------------
__global__ __launch_bounds__(256) void match_a(
    const float4* __restrict__ boxes4,   // N*M (xyxy)
    const float4* __restrict__ priors4,  // P (cxcywh)
    const int* __restrict__ labels,      // N*M
    u16* __restrict__ minfo,             // N*P packed
    u64* __restrict__ combined_part,     // N*BPI*MM
    int* __restrict__ counter)           // [1] -> zeroed here
{
  __shared__ float bx0[MM], by0[MM], bx1[MM], by1[MM], ba[MM];
  __shared__ int lb[MM];
  __shared__ u64 wkey[4][MM];
  const int blk = blockIdx.x % (NN * BPI);   // replica-folded block id
  const int tid = threadIdx.x;
  const int wave = tid >> 6, lane = tid & 63;
  const int n = blk >> 3, part = blk & 7;
  const int c0 = part * CHUNK;
  const int cend = (c0 + CHUNK < PP) ? c0 + CHUNK : PP;

  if (blockIdx.x == 0 && tid == 0) counter[0] = 0;

  if (tid < MM) {
    float4 b = boxes4[n * MM + tid];
    bx0[tid] = b.x; by0[tid] = b.y; bx1[tid] = b.z; by1[tid] = b.w;
    ba[tid] = (b.z - b.x) * (b.w - b.y);
    lb[tid] = labels[n * MM + tid];
  }
  __syncthreads();

  float bi[MM], bd[MM]; int bpp[MM];
#pragma unroll
  for (int m = 0; m < MM; ++m) { bi[m] = 0.0f; bd[m] = 1.0f; bpp[m] = 0; }

#pragma unroll
  for (int i = 0; i < 5; ++i) {
    int p = c0 + tid + i * 256;
    if (p < cend) {
      float4 pr = priors4[p];
      float hw = pr.z * 0.5f, hh = pr.w * 0.5f;
      float px0 = pr.x - hw, py0 = pr.y - hh, px1 = pr.x + hw, py1 = pr.y + hh;
      float pa = (px1 - px0) * (py1 - py0);   // ref rounding
      float pi = -1.0f, pd = 1.0f; int pm = 0;
#pragma unroll
      for (int m = 0; m < MM; ++m) {
        float iw = fminf(bx1[m], px1) - fmaxf(bx0[m], px0);
        float ih = fminf(by1[m], py1) - fmaxf(by0[m], py0);
        iw = fmaxf(iw, 0.0f); ih = fmaxf(ih, 0.0f);
        float inter = iw * ih;
        float den = (ba[m] + pa) - inter;
        bool c1 = inter * pd > pi * den;          // first m wins ties
        pi = c1 ? inter : pi; pd = c1 ? den : pd; pm = c1 ? m : pm;
        bool c2 = inter * bd[m] > bi[m] * den;    // lowest p wins ties
        bi[m] = c2 ? inter : bi[m]; bd[m] = c2 ? den : bd[m];
        bpp[m] = c2 ? p : bpp[m];
      }
      float q = pi / pd;                          // IEEE quotient (ref)
      int lab8 = (q < 0.5f) ? 0 : lb[pm];         // labels 1..90, never 0
      minfo[(size_t)n * PP + p] = (u16)((pm << 8) | lab8);
    }
  }

#pragma unroll
  for (int m = 0; m < MM; ++m) {
    float r = bi[m] / bd[m];
    u64 key = ((u64)__float_as_uint(r) << 32) | (unsigned)(~(unsigned)bpp[m]);
#pragma unroll
    for (int d = 1; d < 64; d <<= 1) {
      u64 o = __shfl_xor(key, d);
      key = (o > key) ? o : key;
    }
    if (lane == 0) wkey[wave][m] = key;
  }
  __syncthreads();
  if (tid < MM) {
    u64 best = wkey[0][tid];
    u64 o1 = wkey[1][tid], o2 = wkey[2][tid], o3 = wkey[3][tid];
    best = (o1 > best) ? o1 : best;
    best = (o2 > best) ? o2 : best;
    best = (o3 > best) ? o3 : best;
    combined_part[blk * MM + tid] = best;
  }
}

// ---------------------------------------------------------------------------
// Kernel B: CE + matching emit + smooth-L1 loc loss (r8 body, grid 1x).
// ---------------------------------------------------------------------------
__global__ __launch_bounds__(BTHR) void ce_kernel(
    const float* __restrict__ scores,        // N*P*C
    const float4* __restrict__ pred_locs4,   // N*P
    const float4* __restrict__ priors4,      // P
    const float4* __restrict__ boxes4,       // N*M
    const int* __restrict__ labels,          // N*M
    const u16* __restrict__ minfo,           // N*P
    const u64* __restrict__ combined_part,   // N*BPI*MM
    float* __restrict__ ce_neg,              // N*P (0 where positive)
    float4* __restrict__ partials)           // [TILES2]
{
  __shared__ unsigned key_lo[2][MM];
  __shared__ int lbl_s[2][MM];
  __shared__ float4 box_s[2][MM];
  __shared__ float4 w8[8];
  const int tid = threadIdx.x;
  const long base = (long)blockIdx.x * ROWS;
  const int n0 = (int)(base / PP);
  const int rem0 = (int)(base - (long)n0 * PP);
  const int r = tid >> 2, l = tid & 3;
  const long row = base + r;

  const int mi = minfo[row];   // broadcast per row

  if (tid < MM) {
    const u64* cp = combined_part + (size_t)n0 * BPI * MM;
    u64 best = cp[tid];
#pragma unroll
    for (int w = 1; w < BPI; ++w) { u64 o = cp[w * MM + tid]; best = (o > best) ? o : best; }
    key_lo[0][tid] = (unsigned)best;
    lbl_s[0][tid]  = labels[n0 * MM + tid];
    box_s[0][tid]  = boxes4[n0 * MM + tid];
  } else if (tid >= 64 && tid < 64 + MM) {
    int j = tid - 64, nn = (n0 + 1 < NN) ? n0 + 1 : NN - 1;
    const u64* cp = combined_part + (size_t)nn * BPI * MM;
    u64 best = cp[j];
#pragma unroll
    for (int w = 1; w < BPI; ++w) { u64 o = cp[w * MM + j]; best = (o > best) ? o : best; }
    key_lo[1][j] = (unsigned)best;
    lbl_s[1][j]  = labels[nn * MM + j];
    box_s[1][j]  = boxes4[nn * MM + j];
  }

  const float* rp = scores + (size_t)row * CC;
  float ss0 = 0.f, ss1 = 0.f, ss2 = 0.f, ss3 = 0.f;
#pragma unroll
  for (int j = 0; j < 23; ++j) {
    int c = l + 4 * j;
    if (c < CC) {
      float e = __expf(rp[c]);
      if ((j & 3) == 0) ss0 += e;
      else if ((j & 3) == 1) ss1 += e;
      else if ((j & 3) == 2) ss2 += e;
      else ss3 += e;
    }
  }
  float s = (ss0 + ss1) + (ss2 + ss3);
  s += __shfl_xor(s, 1);
  s += __shfl_xor(s, 2);

  __syncthreads();   // tables ready

  float cp_ = 0.0f, lp_ = 0.0f; int pos0 = 0, pos1 = 0;
  if (l == 0) {
    const int bn = (rem0 + r >= PP) ? 1 : 0;
    const int p = rem0 + r - bn * PP;
    int mm_ = -1;
    const unsigned want = ~(unsigned)p;
#pragma unroll
    for (int j = 0; j < MM; ++j) if (key_lo[bn][j] == want) mm_ = j;   // last wins
    bool pos; int lab, sm;
    if (mm_ >= 0) { pos = true; sm = mm_; lab = lbl_s[bn][mm_]; }
    else { lab = mi & 0xff; pos = (lab != 0); sm = mi >> 8; }
    float ce = __logf(s) - rp[lab];
    if (pos) {
      cp_ = ce; ce_neg[row] = 0.0f;
      if (bn) pos1 = 1; else pos0 = 1;
      float4 bx = box_s[bn][sm], pr = priors4[p], pl = pred_locs4[row];
      float cx = (bx.x + bx.z) * 0.5f, cy = (bx.y + bx.w) * 0.5f;
      float w = bx.z - bx.x, h = bx.w - bx.y;
      float gx = (cx - pr.x) / (pr.z / 10.0f);
      float gy = (cy - pr.y) / (pr.w / 10.0f);
      float gz = __logf(w / pr.z) * 5.0f;
      float gw = __logf(h / pr.w) * 5.0f;
      float d, a;
      d = pl.x - gx; a = fabsf(d); lp_ += (a < 1.0f) ? 0.5f * d * d : a - 0.5f;
      d = pl.y - gy; a = fabsf(d); lp_ += (a < 1.0f) ? 0.5f * d * d : a - 0.5f;
      d = pl.z - gz; a = fabsf(d); lp_ += (a < 1.0f) ? 0.5f * d * d : a - 0.5f;
      d = pl.w - gw; a = fabsf(d); lp_ += (a < 1.0f) ? 0.5f * d * d : a - 0.5f;
    } else {
      ce_neg[row] = fmaxf(ce, 0.0f);   // >=0 keeps uint order == float order
    }
  }

#pragma unroll
  for (int d = 1; d < 64; d <<= 1) {
    cp_ += __shfl_xor(cp_, d); lp_ += __shfl_xor(lp_, d);
    pos0 += __shfl_xor(pos0, d); pos1 += __shfl_xor(pos1, d);
  }
  if ((tid & 63) == 0)
    w8[tid >> 6] = make_float4(cp_, lp_, (float)pos0, (float)pos1);
  __syncthreads();
  if (tid == 0) {
    float sx = 0.f, sy = 0.f, sz = 0.f, sw = 0.f;
#pragma unroll
    for (int w = 0; w < 8; ++w) { sx += w8[w].x; sy += w8[w].y; sz += w8[w].z; sw += w8[w].w; }
    partials[blockIdx.x] = make_float4(sx, sy, sz, sw);
  }
}

// ---------------------------------------------------------------------------
// Kernel C: hard-negative mining + fused final (r8 body). DIAGNOSTIC: grid
// x HREP; replicas (rep>0) do full identical work + identical per_img writes
// (keeps work live, benign race) but skip the finisher counter.
// ---------------------------------------------------------------------------
__global__ __launch_bounds__(256) void hardneg_kernel(
    const float* __restrict__ ce_neg, const float4* __restrict__ partials,
    float4* __restrict__ per_img, int* __restrict__ counter,
    float* __restrict__ out)
{
  __shared__ int4 cred[2][4];
  __shared__ float wredf[4];
  __shared__ int wcnt[4];
  __shared__ float4 wacc[4];
  __shared__ int last_s;
  const int n = blockIdx.x & (NN - 1);
  const int rep = blockIdx.x >> 6;
  const int tid = threadIdx.x;

  unsigned uv[35];
#pragma unroll
  for (int i = 0; i < 35; ++i) {
    int p = tid + (i << 8);
    uv[i] = (p < PP) ? __float_as_uint(ce_neg[(size_t)n * PP + p]) : 0u;
  }

  float kc = 0.0f, cpo = 0.0f, lpo = 0.0f;
  {
    const int bstart = (n * PP) / ROWS;
    const int bend = ((n + 1) * PP - 1) / ROWS;
    const int ost = (n * PP + ROWS - 1) / ROWS;
    const int oen = ((n + 1) * PP + ROWS - 1) / ROWS;
    for (int b = bstart + tid; b <= bend; b += 256) {
      float4 pb = partials[b];
      int nb0 = (b * ROWS) / PP;
      if (nb0 == n)     kc += pb.z;
      if (nb0 + 1 == n) kc += pb.w;
      if (b >= ost && b < oen) { cpo += pb.x; lpo += pb.y; }
    }
#pragma unroll
    for (int d = 1; d < 64; d <<= 1) {
      kc += __shfl_xor(kc, d); cpo += __shfl_xor(cpo, d); lpo += __shfl_xor(lpo, d);
    }
    if ((tid & 63) == 0) wacc[tid >> 6] = make_float4(kc, cpo, lpo, 0.f);
    __syncthreads();
    kc = wacc[0].x + wacc[1].x + wacc[2].x + wacc[3].x;
    cpo = wacc[0].y + wacc[1].y + wacc[2].y + wacc[3].y;
    lpo = wacc[0].z + wacc[1].z + wacc[2].z + wacc[3].z;
  }
  const float npn = kc;
  const int k = RATIO * (int)(kc + 0.5f);

  float hs = 0.0f;
  if (k >= PP) {
    float s = 0.0f;
#pragma unroll
    for (int i = 0; i < 35; ++i) s += __uint_as_float(uv[i]);
#pragma unroll
    for (int d = 1; d < 64; d <<= 1) s += __shfl_xor(s, d);
    __syncthreads();
    if ((tid & 63) == 0) wredf[tid >> 6] = s;
    __syncthreads();
    hs = wredf[0] + wredf[1] + wredf[2] + wredf[3];
  } else if (k > 0) {
    unsigned lo = 0u, hi = 0x7f7fffffu;
    int it = 0;
    while (lo < hi) {
      unsigned span = hi - lo;
      unsigned q4 = span >> 2;
      unsigned m1, m2, m3;
      if (q4 == 0) { m1 = m2 = m3 = lo + ((span + 1) >> 1); }
      else { m1 = lo + q4; m2 = lo + 2 * q4; m3 = lo + 3 * q4; }
      int a1 = 0, a2 = 0, a3 = 0;
#pragma unroll
      for (int i = 0; i < 35; ++i) {
        unsigned v = uv[i];
        a1 += (v >= m1); a2 += (v >= m2); a3 += (v >= m3);
      }
#pragma unroll
      for (int d = 1; d < 64; d <<= 1) {
        a1 += __shfl_xor(a1, d); a2 += __shfl_xor(a2, d); a3 += __shfl_xor(a3, d);
      }
      const int buf = it & 1;
      if ((tid & 63) == 0) cred[buf][tid >> 6] = make_int4(a1, a2, a3, 0);
      __syncthreads();
      int c1 = 0, c2 = 0, c3 = 0;
#pragma unroll
      for (int w = 0; w < 4; ++w) {
        int4 cc = cred[buf][w];
        c1 += cc.x; c2 += cc.y; c3 += cc.z;
      }
      if (c3 >= k) lo = m3;
      else if (c2 >= k) { lo = m2; hi = m3 - 1; }
      else if (c1 >= k) { lo = m1; hi = m2 - 1; }
      else hi = m1 - 1;
      ++it;
    }
    const float x = __uint_as_float(lo);
    float s = 0.0f; int c = 0;
#pragma unroll
    for (int i = 0; i < 35; ++i) {
      unsigned v = uv[i];
      if (v > lo) { s += __uint_as_float(v); ++c; }
    }
#pragma unroll
    for (int d = 1; d < 64; d <<= 1) { s += __shfl_xor(s, d); c += __shfl_xor(c, d); }
    __syncthreads();
    if ((tid & 63) == 0) { wredf[tid >> 6] = s; wcnt[tid >> 6] = c; }
    __syncthreads();
    hs = (wredf[0] + wredf[1] + wredf[2] + wredf[3]) +
         (float)(k - (wcnt[0] + wcnt[1] + wcnt[2] + wcnt[3])) * x;
  }

  if (tid == 0) {
    per_img[n] = make_float4(cpo, lpo, npn, hs);   // identical across replicas
    if (rep == 0) {
      __threadfence();
      last_s = atomicAdd(counter, 1);
    } else {
      last_s = -1;                                 // replicas never finalize
    }
  }
  __syncthreads();
  if (last_s == NN - 1) {
    __threadfence();
    if (tid < 64) {
      float4 v = per_img[tid];
      float a = v.x, b = v.y, c = v.z, d = v.w;
#pragma unroll
      for (int dd = 1; dd < 64; dd <<= 1) {
        a += __shfl_xor(a, dd); b += __shfl_xor(b, dd);
        c += __shfl_xor(c, dd); d += __shfl_xor(d, dd);
      }
      if (tid == 0) out[0] = (a + d) / c + b / (c * 4.0f);
    }
  }
}

// ---------------------------------------------------------------------------
extern "C" void kernel_launch(void* const* d_in, const int* in_sizes, int n_in,
                              void* d_out, int out_size, void* d_ws, size_t ws_size,
                              hipStream_t stream) {
  const float*  pred_locs   = (const float*)d_in[0];
  const float*  pred_scores = (const float*)d_in[1];
  const float*  boxes       = (const float*)d_in[2];
  const int*    labels      = (const int*)d_in[3];
  const float*  priors      = (const float*)d_in[4];
  float* out = (float*)d_out;

  u16* minfo = (u16*)d_ws;                                        // N*P u16
  float4* partials = (float4*)(minfo + (size_t)NN * PP);          // TILES2
  float*  ce_neg = (float*)(partials + TILES2);                   // N*P
  u64* combined_part = (u64*)(ce_neg + (size_t)NN * PP);          // N*BPI*MM
  float4* per_img = (float4*)(combined_part + NN * BPI * MM);     // NN
  int* counter = (int*)(per_img + NN);                            // 1

  match_a<<<MREP * NN * BPI, 256, 0, stream>>>((const float4*)boxes,
                                               (const float4*)priors, labels,
                                               minfo, combined_part, counter);
  ce_kernel<<<TILES2, BTHR, 0, stream>>>(pred_scores,
                                         (const float4*)pred_locs,
                                         (const float4*)priors,
                                         (const float4*)boxes, labels,
                                         minfo, combined_part,
                                         ce_neg, partials);
  hardneg_kernel<<<HREP * NN, 256, 0, stream>>>(ce_neg, partials, per_img,
                                                counter, out);
}

// Round 12
// 81.683 us; speedup vs baseline: 5.4238x; 5.4238x over previous
//
#include <hip/hip_runtime.h>

#define NN 64
#define PP 8732
#define CC 91
#define MM 20
#define RATIO 3
#define BPI 32                   // match blocks per image
#define CHUNK 273                // ceil(PP / BPI); last part gets 269
#define ROWS 128                 // ce rows per block
#define BTHR 512                 // ce threads per block
#define TILES2 ((NN * PP) / ROWS)   // 4366 ce tiles

typedef unsigned long long u64;
typedef unsigned short u16;

// ---------------------------------------------------------------------------
// Kernel A: matching, occupancy-restructured.
// 32 blocks/image x 256 threads; wave w owns objects [5w, 5w+5): per-object
// butterfly is 5 keys/thread (not 20), per-prior argmax combined across the
// 4 waves via LDS with exact cross-mul compares (wave order == ascending m;
// strict > keeps ref's first-max tie-break). Emits packed u16
// (obj<<8 | label-if-positive); per-object best prior in block-exclusive
// combined_part slices (no atomics, no zeroing).
// ---------------------------------------------------------------------------
__global__ __launch_bounds__(256) void match_b(
    const float4* __restrict__ boxes4,   // N*M (xyxy)
    const float4* __restrict__ priors4,  // P (cxcywh)
    const int* __restrict__ labels,      // N*M
    u16* __restrict__ minfo,             // N*P packed
    u64* __restrict__ combined_part,     // N*BPI*MM
    int* __restrict__ counter)           // [1] -> zeroed here
{
  __shared__ float pi_s[4][CHUNK];       // per-wave per-prior best inter
  __shared__ float pd_s[4][CHUNK];       // ... and denominator
  __shared__ short pm_s[4][CHUNK];       // ... and object (global m)
  __shared__ int lb[MM];
  const int blk = blockIdx.x, tid = threadIdx.x;
  const int wave = tid >> 6, lane = tid & 63;
  const int n = blk >> 5, part = blk & 31;
  const int c0 = part * CHUNK;
  const int cend = (c0 + CHUNK < PP) ? c0 + CHUNK : PP;
  const int clen = cend - c0;

  if (blockIdx.x == 0 && tid == 0) counter[0] = 0;
  if (tid < MM) lb[tid] = labels[n * MM + tid];

  // wave's 5 objects -> registers (uniform per wave)
  float obx0[5], oby0[5], obx1[5], oby1[5], oba[5];
#pragma unroll
  for (int j = 0; j < 5; ++j) {
    float4 b = boxes4[n * MM + wave * 5 + j];
    obx0[j] = b.x; oby0[j] = b.y; obx1[j] = b.z; oby1[j] = b.w;
    oba[j] = (b.z - b.x) * (b.w - b.y);
  }

  float bi[5], bd[5]; int bpp[5];
#pragma unroll
  for (int j = 0; j < 5; ++j) { bi[j] = 0.0f; bd[j] = 1.0f; bpp[j] = 0; }

  // phase 1: every wave scans the whole chunk against ITS 5 objects
#pragma unroll
  for (int i = 0; i < 5; ++i) {
    int pc = lane + (i << 6);
    if (pc < clen) {
      int p = c0 + pc;
      float4 pr = priors4[p];
      float hw = pr.z * 0.5f, hh = pr.w * 0.5f;
      float px0 = pr.x - hw, py0 = pr.y - hh, px1 = pr.x + hw, py1 = pr.y + hh;
      float pa = (px1 - px0) * (py1 - py0);   // ref rounding
      float pi = -1.0f, pd = 1.0f; int pm = 0;
#pragma unroll
      for (int j = 0; j < 5; ++j) {
        float iw = fminf(obx1[j], px1) - fmaxf(obx0[j], px0);
        float ih = fminf(oby1[j], py1) - fmaxf(oby0[j], py0);
        iw = fmaxf(iw, 0.0f); ih = fmaxf(ih, 0.0f);
        float inter = iw * ih;
        float den = (oba[j] + pa) - inter;
        bool cA = inter * pd > pi * den;          // first j wins ties
        pi = cA ? inter : pi; pd = cA ? den : pd;
        pm = cA ? (wave * 5 + j) : pm;
        bool cB = inter * bd[j] > bi[j] * den;    // lowest p wins ties
        bi[j] = cB ? inter : bi[j]; bd[j] = cB ? den : bd[j];
        bpp[j] = cB ? p : bpp[j];
      }
      pi_s[wave][pc] = pi; pd_s[wave][pc] = pd; pm_s[wave][pc] = (short)pm;
    }
  }

  // phase 2: per-object butterfly over the wave (5 keys), one division each
#pragma unroll
  for (int j = 0; j < 5; ++j) {
    float r = bi[j] / bd[j];                   // IEEE quotient, >=0
    u64 key = ((u64)__float_as_uint(r) << 32) | (unsigned)(~(unsigned)bpp[j]);
#pragma unroll
    for (int d = 1; d < 64; d <<= 1) {
      u64 o = __shfl_xor(key, d);
      key = (o > key) ? o : key;
    }
    if (lane == 0) combined_part[blk * MM + wave * 5 + j] = key;
  }
  __syncthreads();

  // phase 3: combine 4 waves per prior (ascending m, strict >) + emit minfo
  for (int pc = tid; pc < clen; pc += 256) {
    float pi = pi_s[0][pc], pd = pd_s[0][pc]; int pm = pm_s[0][pc];
#pragma unroll
    for (int w = 1; w < 4; ++w) {
      float qi = pi_s[w][pc], qd = pd_s[w][pc];
      bool c = qi * pd > pi * qd;               // later m only if strictly >
      int qm = pm_s[w][pc];
      pi = c ? qi : pi; pd = c ? qd : pd; pm = c ? qm : pm;
    }
    float q = pi / pd;                          // IEEE quotient (ref)
    int lab8 = (q < 0.5f) ? 0 : lb[pm];         // labels 1..90, never 0
    minfo[(size_t)n * PP + c0 + pc] = (u16)((pm << 8) | lab8);
  }
}

// ---------------------------------------------------------------------------
// Kernel B: CE + matching emit + smooth-L1 loc loss (r8 body; direct-global
// score path). 128 rows/block, 512 threads; table-stage folds BPI=32 parts.
// partials[b] = (conf_pos_sum, loc_sum, n_pos img n0, n_pos img n0+1).
// ---------------------------------------------------------------------------
__global__ __launch_bounds__(BTHR) void ce_kernel(
    const float* __restrict__ scores,        // N*P*C
    const float4* __restrict__ pred_locs4,   // N*P
    const float4* __restrict__ priors4,      // P
    const float4* __restrict__ boxes4,       // N*M
    const int* __restrict__ labels,          // N*M
    const u16* __restrict__ minfo,           // N*P
    const u64* __restrict__ combined_part,   // N*BPI*MM
    float* __restrict__ ce_neg,              // N*P (0 where positive)
    float4* __restrict__ partials)           // [TILES2]
{
  __shared__ unsigned key_lo[2][MM];
  __shared__ int lbl_s[2][MM];
  __shared__ float4 box_s[2][MM];
  __shared__ float4 w8[8];
  const int tid = threadIdx.x;
  const long base = (long)blockIdx.x * ROWS;
  const int n0 = (int)(base / PP);
  const int rem0 = (int)(base - (long)n0 * PP);
  const int r = tid >> 2, l = tid & 3;
  const long row = base + r;

  const int mi = minfo[row];   // broadcast per row

  if (tid < MM) {
    const u64* cp = combined_part + (size_t)n0 * BPI * MM;
    u64 best = cp[tid];
#pragma unroll
    for (int w = 1; w < BPI; ++w) { u64 o = cp[w * MM + tid]; best = (o > best) ? o : best; }
    key_lo[0][tid] = (unsigned)best;
    lbl_s[0][tid]  = labels[n0 * MM + tid];
    box_s[0][tid]  = boxes4[n0 * MM + tid];
  } else if (tid >= 64 && tid < 64 + MM) {
    int j = tid - 64, nn = (n0 + 1 < NN) ? n0 + 1 : NN - 1;
    const u64* cp = combined_part + (size_t)nn * BPI * MM;
    u64 best = cp[j];
#pragma unroll
    for (int w = 1; w < BPI; ++w) { u64 o = cp[w * MM + j]; best = (o > best) ? o : best; }
    key_lo[1][j] = (unsigned)best;
    lbl_s[1][j]  = labels[nn * MM + j];
    box_s[1][j]  = boxes4[nn * MM + j];
  }

  const float* rp = scores + (size_t)row * CC;
  float ss0 = 0.f, ss1 = 0.f, ss2 = 0.f, ss3 = 0.f;
#pragma unroll
  for (int j = 0; j < 23; ++j) {
    int c = l + 4 * j;
    if (c < CC) {
      float e = __expf(rp[c]);
      if ((j & 3) == 0) ss0 += e;
      else if ((j & 3) == 1) ss1 += e;
      else if ((j & 3) == 2) ss2 += e;
      else ss3 += e;
    }
  }
  float s = (ss0 + ss1) + (ss2 + ss3);
  s += __shfl_xor(s, 1);
  s += __shfl_xor(s, 2);

  __syncthreads();   // tables ready

  float cp_ = 0.0f, lp_ = 0.0f; int pos0 = 0, pos1 = 0;
  if (l == 0) {
    const int bn = (rem0 + r >= PP) ? 1 : 0;
    const int p = rem0 + r - bn * PP;
    int mm_ = -1;
    const unsigned want = ~(unsigned)p;
#pragma unroll
    for (int j = 0; j < MM; ++j) if (key_lo[bn][j] == want) mm_ = j;   // last wins
    bool pos; int lab, sm;
    if (mm_ >= 0) { pos = true; sm = mm_; lab = lbl_s[bn][mm_]; }
    else { lab = mi & 0xff; pos = (lab != 0); sm = mi >> 8; }
    float ce = __logf(s) - rp[lab];
    if (pos) {
      cp_ = ce; ce_neg[row] = 0.0f;
      if (bn) pos1 = 1; else pos0 = 1;
      float4 bx = box_s[bn][sm], pr = priors4[p], pl = pred_locs4[row];
      float cx = (bx.x + bx.z) * 0.5f, cy = (bx.y + bx.w) * 0.5f;
      float w = bx.z - bx.x, h = bx.w - bx.y;
      float gx = (cx - pr.x) / (pr.z / 10.0f);
      float gy = (cy - pr.y) / (pr.w / 10.0f);
      float gz = __logf(w / pr.z) * 5.0f;
      float gw = __logf(h / pr.w) * 5.0f;
      float d, a;
      d = pl.x - gx; a = fabsf(d); lp_ += (a < 1.0f) ? 0.5f * d * d : a - 0.5f;
      d = pl.y - gy; a = fabsf(d); lp_ += (a < 1.0f) ? 0.5f * d * d : a - 0.5f;
      d = pl.z - gz; a = fabsf(d); lp_ += (a < 1.0f) ? 0.5f * d * d : a - 0.5f;
      d = pl.w - gw; a = fabsf(d); lp_ += (a < 1.0f) ? 0.5f * d * d : a - 0.5f;
    } else {
      ce_neg[row] = fmaxf(ce, 0.0f);   // >=0 keeps uint order == float order
    }
  }

#pragma unroll
  for (int d = 1; d < 64; d <<= 1) {
    cp_ += __shfl_xor(cp_, d); lp_ += __shfl_xor(lp_, d);
    pos0 += __shfl_xor(pos0, d); pos1 += __shfl_xor(pos1, d);
  }
  if ((tid & 63) == 0)
    w8[tid >> 6] = make_float4(cp_, lp_, (float)pos0, (float)pos1);
  __syncthreads();
  if (tid == 0) {
    float sx = 0.f, sy = 0.f, sz = 0.f, sw = 0.f;
#pragma unroll
    for (int w = 0; w < 8; ++w) { sx += w8[w].x; sy += w8[w].y; sz += w8[w].z; sw += w8[w].w; }
    partials[blockIdx.x] = make_float4(sx, sy, sz, sw);
  }
}

// ---------------------------------------------------------------------------
// Kernel C: hard-negative mining (4-ary bisection) + fused final (r8 body).
// ---------------------------------------------------------------------------
__global__ __launch_bounds__(256) void hardneg_kernel(
    const float* __restrict__ ce_neg, const float4* __restrict__ partials,
    float4* __restrict__ per_img, int* __restrict__ counter,
    float* __restrict__ out)
{
  __shared__ int4 cred[2][4];
  __shared__ float wredf[4];
  __shared__ int wcnt[4];
  __shared__ float4 wacc[4];
  __shared__ int last_s;
  const int n = blockIdx.x, tid = threadIdx.x;

  unsigned uv[35];
#pragma unroll
  for (int i = 0; i < 35; ++i) {
    int p = tid + (i << 8);
    uv[i] = (p < PP) ? __float_as_uint(ce_neg[(size_t)n * PP + p]) : 0u;
  }

  float kc = 0.0f, cpo = 0.0f, lpo = 0.0f;
  {
    const int bstart = (n * PP) / ROWS;
    const int bend = ((n + 1) * PP - 1) / ROWS;
    const int ost = (n * PP + ROWS - 1) / ROWS;
    const int oen = ((n + 1) * PP + ROWS - 1) / ROWS;
    for (int b = bstart + tid; b <= bend; b += 256) {
      float4 pb = partials[b];
      int nb0 = (b * ROWS) / PP;
      if (nb0 == n)     kc += pb.z;
      if (nb0 + 1 == n) kc += pb.w;
      if (b >= ost && b < oen) { cpo += pb.x; lpo += pb.y; }
    }
#pragma unroll
    for (int d = 1; d < 64; d <<= 1) {
      kc += __shfl_xor(kc, d); cpo += __shfl_xor(cpo, d); lpo += __shfl_xor(lpo, d);
    }
    if ((tid & 63) == 0) wacc[tid >> 6] = make_float4(kc, cpo, lpo, 0.f);
    __syncthreads();
    kc = wacc[0].x + wacc[1].x + wacc[2].x + wacc[3].x;
    cpo = wacc[0].y + wacc[1].y + wacc[2].y + wacc[3].y;
    lpo = wacc[0].z + wacc[1].z + wacc[2].z + wacc[3].z;
  }
  const float npn = kc;
  const int k = RATIO * (int)(kc + 0.5f);

  float hs = 0.0f;
  if (k >= PP) {
    float s = 0.0f;
#pragma unroll
    for (int i = 0; i < 35; ++i) s += __uint_as_float(uv[i]);
#pragma unroll
    for (int d = 1; d < 64; d <<= 1) s += __shfl_xor(s, d);
    __syncthreads();
    if ((tid & 63) == 0) wredf[tid >> 6] = s;
    __syncthreads();
    hs = wredf[0] + wredf[1] + wredf[2] + wredf[3];
  } else if (k > 0) {
    unsigned lo = 0u, hi = 0x7f7fffffu;
    int it = 0;
    while (lo < hi) {
      unsigned span = hi - lo;
      unsigned q4 = span >> 2;
      unsigned m1, m2, m3;
      if (q4 == 0) { m1 = m2 = m3 = lo + ((span + 1) >> 1); }
      else { m1 = lo + q4; m2 = lo + 2 * q4; m3 = lo + 3 * q4; }
      int a1 = 0, a2 = 0, a3 = 0;
#pragma unroll
      for (int i = 0; i < 35; ++i) {
        unsigned v = uv[i];
        a1 += (v >= m1); a2 += (v >= m2); a3 += (v >= m3);
      }
#pragma unroll
      for (int d = 1; d < 64; d <<= 1) {
        a1 += __shfl_xor(a1, d); a2 += __shfl_xor(a2, d); a3 += __shfl_xor(a3, d);
      }
      const int buf = it & 1;
      if ((tid & 63) == 0) cred[buf][tid >> 6] = make_int4(a1, a2, a3, 0);
      __syncthreads();
      int c1 = 0, c2 = 0, c3 = 0;
#pragma unroll
      for (int w = 0; w < 4; ++w) {
        int4 cc = cred[buf][w];
        c1 += cc.x; c2 += cc.y; c3 += cc.z;
      }
      if (c3 >= k) lo = m3;
      else if (c2 >= k) { lo = m2; hi = m3 - 1; }
      else if (c1 >= k) { lo = m1; hi = m2 - 1; }
      else hi = m1 - 1;
      ++it;
    }
    const float x = __uint_as_float(lo);
    float s = 0.0f; int c = 0;
#pragma unroll
    for (int i = 0; i < 35; ++i) {
      unsigned v = uv[i];
      if (v > lo) { s += __uint_as_float(v); ++c; }
    }
#pragma unroll
    for (int d = 1; d < 64; d <<= 1) { s += __shfl_xor(s, d); c += __shfl_xor(c, d); }
    __syncthreads();
    if ((tid & 63) == 0) { wredf[tid >> 6] = s; wcnt[tid >> 6] = c; }
    __syncthreads();
    hs = (wredf[0] + wredf[1] + wredf[2] + wredf[3]) +
         (float)(k - (wcnt[0] + wcnt[1] + wcnt[2] + wcnt[3])) * x;
  }

  if (tid == 0) {
    per_img[n] = make_float4(cpo, lpo, npn, hs);
    __threadfence();
    last_s = atomicAdd(counter, 1);
  }
  __syncthreads();
  if (last_s == NN - 1) {
    __threadfence();
    if (tid < 64) {
      float4 v = per_img[tid];
      float a = v.x, b = v.y, c = v.z, d = v.w;
#pragma unroll
      for (int dd = 1; dd < 64; dd <<= 1) {
        a += __shfl_xor(a, dd); b += __shfl_xor(b, dd);
        c += __shfl_xor(c, dd); d += __shfl_xor(d, dd);
      }
      if (tid == 0) out[0] = (a + d) / c + b / (c * 4.0f);
    }
  }
}

// ---------------------------------------------------------------------------
extern "C" void kernel_launch(void* const* d_in, const int* in_sizes, int n_in,
                              void* d_out, int out_size, void* d_ws, size_t ws_size,
                              hipStream_t stream) {
  const float*  pred_locs   = (const float*)d_in[0];
  const float*  pred_scores = (const float*)d_in[1];
  const float*  boxes       = (const float*)d_in[2];
  const int*    labels      = (const int*)d_in[3];
  const float*  priors      = (const float*)d_in[4];
  float* out = (float*)d_out;

  u16* minfo = (u16*)d_ws;                                        // N*P u16
  float4* partials = (float4*)(minfo + (size_t)NN * PP);          // TILES2
  float*  ce_neg = (float*)(partials + TILES2);                   // N*P
  u64* combined_part = (u64*)(ce_neg + (size_t)NN * PP);          // N*BPI*MM
  float4* per_img = (float4*)(combined_part + (size_t)NN * BPI * MM); // NN
  int* counter = (int*)(per_img + NN);                            // 1

  match_b<<<NN * BPI, 256, 0, stream>>>((const float4*)boxes,
                                        (const float4*)priors, labels,
                                        minfo, combined_part, counter);
  ce_kernel<<<TILES2, BTHR, 0, stream>>>(pred_scores,
                                         (const float4*)pred_locs,
                                         (const float4*)priors,
                                         (const float4*)boxes, labels,
                                         minfo, combined_part,
                                         ce_neg, partials);
  hardneg_kernel<<<NN, 256, 0, stream>>>(ce_neg, partials, per_img,
                                         counter, out);
}